// Round 18
// baseline (354.907 us; speedup 1.0000x reference)
//
#include <hip/hip_runtime.h>

#define T_LEN 1024
#define C_DIM 2048
#define H_NUM 32
#define HS_DIM 64
#define FF_DIM 7168
#define CHUNK 64
#define NCHUNK (T_LEN / CHUNK)

typedef __attribute__((ext_vector_type(4))) float f32x4;
typedef __attribute__((ext_vector_type(8))) short short8;
typedef __attribute__((ext_vector_type(4))) unsigned int u32x4;

__device__ __forceinline__ unsigned short f2bf(float f) {
  unsigned int u = __float_as_uint(f);
  unsigned int r = (u + 0x7FFFu + ((u >> 16) & 1u)) >> 16;
  return (unsigned short)r;
}

__device__ __forceinline__ float bf2f(short s) {
  return __uint_as_float(((unsigned int)(unsigned short)s) << 16);
}

// HW packed f32->bf16 (RNE)
__device__ __forceinline__ unsigned int cvtpk(float a, float b) {
  unsigned int r;
  asm("v_cvt_pk_bf16_f32 %0, %1, %2" : "=v"(r) : "v"(a), "v"(b));
  return r;
}

__device__ __forceinline__ short8 pack_bf8(float4 a, float4 b) {
  short8 o;
  o[0] = (short)f2bf(a.x); o[1] = (short)f2bf(a.y);
  o[2] = (short)f2bf(a.z); o[3] = (short)f2bf(a.w);
  o[4] = (short)f2bf(b.x); o[5] = (short)f2bf(b.y);
  o[6] = (short)f2bf(b.z); o[7] = (short)f2bf(b.w);
  return o;
}

__device__ __forceinline__ void gl_lds16(const void* g, void* l) {
  __builtin_amdgcn_global_load_lds(
      (const __attribute__((address_space(1))) unsigned int*)g,
      (__attribute__((address_space(3))) unsigned int*)l, 16, 0, 0);
}

// ---------------- fused LN + TimeMix token-shift (4 bf16 outputs) ----------------
__global__ __launch_bounds__(256) void ln_mix_att(const float* __restrict__ x,
                                                  const float* __restrict__ shift,
                                                  const float* __restrict__ lw,
                                                  const float* __restrict__ lb,
                                                  const float* __restrict__ mr,
                                                  const float* __restrict__ mk,
                                                  const float* __restrict__ mv,
                                                  const float* __restrict__ mg,
                                                  unsigned short* __restrict__ xr,
                                                  unsigned short* __restrict__ xk,
                                                  unsigned short* __restrict__ xv,
                                                  unsigned short* __restrict__ xg) {
  const int t = blockIdx.x;
  const int tid = threadIdx.x;
  const int c0 = tid * 8;
  const float* xrow = x + (size_t)t * C_DIM;
  float cur[8], prv[8];
  *(float4*)&cur[0] = *(const float4*)(xrow + c0);
  *(float4*)&cur[4] = *(const float4*)(xrow + c0 + 4);
  const bool hp = (t > 0);
  const float* prow = hp ? (xrow - C_DIM) : (shift + 0);
  *(float4*)&prv[0] = *(const float4*)(prow + c0);
  *(float4*)&prv[4] = *(const float4*)(prow + c0 + 4);
  float s0 = 0.f, q0 = 0.f, s1 = 0.f, q1 = 0.f;
#pragma unroll
  for (int i = 0; i < 8; ++i) {
    s0 += cur[i]; q0 = __builtin_fmaf(cur[i], cur[i], q0);
    s1 += prv[i]; q1 = __builtin_fmaf(prv[i], prv[i], q1);
  }
#pragma unroll
  for (int o = 1; o < 64; o <<= 1) {
    s0 += __shfl_xor(s0, o); q0 += __shfl_xor(q0, o);
    s1 += __shfl_xor(s1, o); q1 += __shfl_xor(q1, o);
  }
  __shared__ float red[4][4];
  const int wave = tid >> 6, lane = tid & 63;
  if (lane == 0) { red[wave][0] = s0; red[wave][1] = q0; red[wave][2] = s1; red[wave][3] = q1; }
  __syncthreads();
  s0 = red[0][0] + red[1][0] + red[2][0] + red[3][0];
  q0 = red[0][1] + red[1][1] + red[2][1] + red[3][1];
  s1 = red[0][2] + red[1][2] + red[2][2] + red[3][2];
  q1 = red[0][3] + red[1][3] + red[2][3] + red[3][3];
  const float mean0 = s0 * (1.f / C_DIM);
  const float inv0 = rsqrtf(q0 * (1.f / C_DIM) - mean0 * mean0 + 1e-5f);
  const float mean1 = s1 * (1.f / C_DIM);
  const float inv1 = rsqrtf(q1 * (1.f / C_DIM) - mean1 * mean1 + 1e-5f);
  float w8[8], b8[8];
  *(float4*)&w8[0] = *(const float4*)(lw + c0);
  *(float4*)&w8[4] = *(const float4*)(lw + c0 + 4);
  *(float4*)&b8[0] = *(const float4*)(lb + c0);
  *(float4*)&b8[4] = *(const float4*)(lb + c0 + 4);
  float curn[8], prvn[8];
#pragma unroll
  for (int i = 0; i < 8; ++i) {
    curn[i] = (cur[i] - mean0) * inv0 * w8[i] + b8[i];
    prvn[i] = hp ? ((prv[i] - mean1) * inv1 * w8[i] + b8[i]) : prv[i];
  }
  const size_t idx = (size_t)t * C_DIM + c0;
  const float* mixp[4] = {mr, mk, mv, mg};
  unsigned short* dst[4] = {xr, xk, xv, xg};
#pragma unroll
  for (int which = 0; which < 4; ++which) {
    const float* m = mixp[which];
    float o[8];
#pragma unroll
    for (int i = 0; i < 8; ++i) {
      float a = m[c0 + i];
      o[i] = curn[i] * a + prvn[i] * (1.f - a);
    }
    *(short8*)(dst[which] + idx) = pack_bf8(*(float4*)&o[0], *(float4*)&o[4]);
  }
}

// ------- fused (xnew = goC + P0+P1+P2 + x) + LN2 + ChannelMix mixes; writes xnew -------
__global__ __launch_bounds__(256) void ln_mix_cm_f(const float* __restrict__ goC,
                                                   const float* __restrict__ P,
                                                   const float* __restrict__ x,
                                                   const float* __restrict__ shift,
                                                   const float* __restrict__ lw,
                                                   const float* __restrict__ lb,
                                                   const float* __restrict__ mk,
                                                   const float* __restrict__ mr,
                                                   float* __restrict__ xnewF,
                                                   unsigned short* __restrict__ xk2,
                                                   unsigned short* __restrict__ xr2) {
  const int t = blockIdx.x;
  const int tid = threadIdx.x;
  const int c0 = tid * 8;
  const size_t rc = (size_t)t * C_DIM + c0;
  const size_t R = (size_t)T_LEN * C_DIM;
  float cur[8], prv[8];
  {
    float4 g1 = *(const float4*)(goC + rc), g2 = *(const float4*)(goC + rc + 4);
    float4 p1 = *(const float4*)(P + rc), p2 = *(const float4*)(P + rc + 4);
    float4 q1 = *(const float4*)(P + R + rc), q2 = *(const float4*)(P + R + rc + 4);
    float4 r1 = *(const float4*)(P + 2 * R + rc), r2 = *(const float4*)(P + 2 * R + rc + 4);
    float4 x1 = *(const float4*)(x + rc), x2 = *(const float4*)(x + rc + 4);
    cur[0] = g1.x + p1.x + q1.x + r1.x + x1.x;
    cur[1] = g1.y + p1.y + q1.y + r1.y + x1.y;
    cur[2] = g1.z + p1.z + q1.z + r1.z + x1.z;
    cur[3] = g1.w + p1.w + q1.w + r1.w + x1.w;
    cur[4] = g2.x + p2.x + q2.x + r2.x + x2.x;
    cur[5] = g2.y + p2.y + q2.y + r2.y + x2.y;
    cur[6] = g2.z + p2.z + q2.z + r2.z + x2.z;
    cur[7] = g2.w + p2.w + q2.w + r2.w + x2.w;
  }
  const bool hp = (t > 0);
  if (hp) {
    const size_t rp = rc - C_DIM;
    float4 g1 = *(const float4*)(goC + rp), g2 = *(const float4*)(goC + rp + 4);
    float4 p1 = *(const float4*)(P + rp), p2 = *(const float4*)(P + rp + 4);
    float4 q1 = *(const float4*)(P + R + rp), q2 = *(const float4*)(P + R + rp + 4);
    float4 r1 = *(const float4*)(P + 2 * R + rp), r2 = *(const float4*)(P + 2 * R + rp + 4);
    float4 x1 = *(const float4*)(x + rp), x2 = *(const float4*)(x + rp + 4);
    prv[0] = g1.x + p1.x + q1.x + r1.x + x1.x;
    prv[1] = g1.y + p1.y + q1.y + r1.y + x1.y;
    prv[2] = g1.z + p1.z + q1.z + r1.z + x1.z;
    prv[3] = g1.w + p1.w + q1.w + r1.w + x1.w;
    prv[4] = g2.x + p2.x + q2.x + r2.x + x2.x;
    prv[5] = g2.y + p2.y + q2.y + r2.y + x2.y;
    prv[6] = g2.z + p2.z + q2.z + r2.z + x2.z;
    prv[7] = g2.w + p2.w + q2.w + r2.w + x2.w;
  } else {
    *(float4*)&prv[0] = *(const float4*)(shift + c0);
    *(float4*)&prv[4] = *(const float4*)(shift + c0 + 4);
  }
  *(float4*)(xnewF + rc) = *(float4*)&cur[0];
  *(float4*)(xnewF + rc + 4) = *(float4*)&cur[4];

  float s0 = 0.f, q0 = 0.f, s1 = 0.f, q1 = 0.f;
#pragma unroll
  for (int i = 0; i < 8; ++i) {
    s0 += cur[i]; q0 = __builtin_fmaf(cur[i], cur[i], q0);
    s1 += prv[i]; q1 = __builtin_fmaf(prv[i], prv[i], q1);
  }
#pragma unroll
  for (int o = 1; o < 64; o <<= 1) {
    s0 += __shfl_xor(s0, o); q0 += __shfl_xor(q0, o);
    s1 += __shfl_xor(s1, o); q1 += __shfl_xor(q1, o);
  }
  __shared__ float red[4][4];
  const int wave = tid >> 6, lane = tid & 63;
  if (lane == 0) { red[wave][0] = s0; red[wave][1] = q0; red[wave][2] = s1; red[wave][3] = q1; }
  __syncthreads();
  s0 = red[0][0] + red[1][0] + red[2][0] + red[3][0];
  q0 = red[0][1] + red[1][1] + red[2][1] + red[3][1];
  s1 = red[0][2] + red[1][2] + red[2][2] + red[3][2];
  q1 = red[0][3] + red[1][3] + red[2][3] + red[3][3];
  const float mean0 = s0 * (1.f / C_DIM);
  const float inv0 = rsqrtf(q0 * (1.f / C_DIM) - mean0 * mean0 + 1e-5f);
  const float mean1 = s1 * (1.f / C_DIM);
  const float inv1 = rsqrtf(q1 * (1.f / C_DIM) - mean1 * mean1 + 1e-5f);
  float w8[8], b8[8];
  *(float4*)&w8[0] = *(const float4*)(lw + c0);
  *(float4*)&w8[4] = *(const float4*)(lw + c0 + 4);
  *(float4*)&b8[0] = *(const float4*)(lb + c0);
  *(float4*)&b8[4] = *(const float4*)(lb + c0 + 4);
  float ok[8], orr[8];
#pragma unroll
  for (int i = 0; i < 8; ++i) {
    const float cn = (cur[i] - mean0) * inv0 * w8[i] + b8[i];
    const float pn = hp ? ((prv[i] - mean1) * inv1 * w8[i] + b8[i]) : prv[i];
    float a = mk[c0 + i];
    ok[i] = cn * a + pn * (1.f - a);
    a = mr[c0 + i];
    orr[i] = cn * a + pn * (1.f - a);
  }
  *(short8*)(xk2 + rc) = pack_bf8(*(float4*)&ok[0], *(float4*)&ok[4]);
  *(short8*)(xr2 + rc) = pack_bf8(*(float4*)&orr[0], *(float4*)&orr[4]);
}

// ======================= Chunk-parallel WKV v5 scan (bf16 in, f32 state) =======================
__global__ __launch_bounds__(256) void wkv_chunk_sum(const unsigned short* __restrict__ kin,
                                                     const unsigned short* __restrict__ vin,
                                                     const float* __restrict__ decay,
                                                     float* __restrict__ Abuf) {
  const int c = blockIdx.x, h = blockIdx.y;
  const int tid = threadIdx.x;
  const int vcol = tid >> 2, kg = tid & 3;
  __shared__ float ks[CHUNK][HS_DIM];
  __shared__ float vs[CHUNK][HS_DIM];
  for (int i = tid; i < CHUNK * HS_DIM / 8; i += 256) {
    int row = i >> 3, q = i & 7;
    size_t g = (size_t)(c * CHUNK + row) * C_DIM + h * HS_DIM + q * 8;
    short8 kv = *(const short8*)(kin + g);
    short8 vv = *(const short8*)(vin + g);
#pragma unroll
    for (int j = 0; j < 8; ++j) {
      ks[row][q * 8 + j] = bf2f(kv[j]);
      vs[row][q * 8 + j] = bf2f(vv[j]);
    }
  }
  float w16[16], s[16];
#pragma unroll
  for (int j = 0; j < 16; ++j) {
    w16[j] = expf(-expf(decay[h * HS_DIM + kg * 16 + j]));
    s[j] = 0.f;
  }
  __syncthreads();
  for (int t = 0; t < CHUNK; ++t) {
    const float vt = vs[t][vcol];
    const float4* kp = (const float4*)&ks[t][kg * 16];
#pragma unroll
    for (int q = 0; q < 4; ++q) {
      float4 k4 = kp[q];
      s[q * 4 + 0] = __builtin_fmaf(s[q * 4 + 0], w16[q * 4 + 0], k4.x * vt);
      s[q * 4 + 1] = __builtin_fmaf(s[q * 4 + 1], w16[q * 4 + 1], k4.y * vt);
      s[q * 4 + 2] = __builtin_fmaf(s[q * 4 + 2], w16[q * 4 + 2], k4.z * vt);
      s[q * 4 + 3] = __builtin_fmaf(s[q * 4 + 3], w16[q * 4 + 3], k4.w * vt);
    }
  }
  const size_t base = (((size_t)h * NCHUNK + c) * HS_DIM + kg * 16) * HS_DIM + vcol;
#pragma unroll
  for (int j = 0; j < 16; ++j) Abuf[base + (size_t)j * HS_DIM] = s[j];
}

__global__ __launch_bounds__(256) void wkv_chain(const float* __restrict__ Abuf,
                                                 const float* __restrict__ s0,
                                                 const float* __restrict__ decay,
                                                 float* __restrict__ Sbuf) {
  const int h = blockIdx.x;
  const int tid = threadIdx.x;
  const int vcol = tid >> 2, kg = tid & 3;
  float wL[16], s[16];
#pragma unroll
  for (int j = 0; j < 16; ++j) {
    int kidx = kg * 16 + j;
    wL[j] = expf(-(float)CHUNK * expf(decay[h * HS_DIM + kidx]));
    s[j] = s0[((size_t)h * HS_DIM + kidx) * HS_DIM + vcol];
  }
  for (int c = 0; c < NCHUNK; ++c) {
    const size_t base = (((size_t)h * NCHUNK + c) * HS_DIM + kg * 16) * HS_DIM + vcol;
#pragma unroll
    for (int j = 0; j < 16; ++j) {
      Sbuf[base + (size_t)j * HS_DIM] = s[j];
      s[j] = __builtin_fmaf(s[j], wL[j], Abuf[base + (size_t)j * HS_DIM]);
    }
  }
}

// Pass C fused with GroupNorm(out/8)*gn_w+gn_b times silu(g) -> zg bf16
__global__ __launch_bounds__(256) void wkv_chunk_out_gn(
    const unsigned short* __restrict__ kin, const unsigned short* __restrict__ vin,
    const unsigned short* __restrict__ rin, const float* __restrict__ decay,
    const float* __restrict__ faaaa, const float* __restrict__ Sbuf,
    const unsigned short* __restrict__ gpre, const float* __restrict__ gw,
    const float* __restrict__ gb, unsigned short* __restrict__ zg) {
  const int c = blockIdx.x, h = blockIdx.y;
  const int tid = threadIdx.x;
  const int vcol = tid >> 2, kg = tid & 3;
  __shared__ float ks[CHUNK][HS_DIM];
  __shared__ float rs[CHUNK][HS_DIM];
  __shared__ float vs[CHUNK][HS_DIM];
  __shared__ float os[CHUNK][HS_DIM + 4];
  for (int i = tid; i < CHUNK * HS_DIM / 8; i += 256) {
    int row = i >> 3, q = i & 7;
    size_t g = (size_t)(c * CHUNK + row) * C_DIM + h * HS_DIM + q * 8;
    short8 kv = *(const short8*)(kin + g);
    short8 rv = *(const short8*)(rin + g);
    short8 vv = *(const short8*)(vin + g);
#pragma unroll
    for (int j = 0; j < 8; ++j) {
      ks[row][q * 8 + j] = bf2f(kv[j]);
      rs[row][q * 8 + j] = bf2f(rv[j]);
      vs[row][q * 8 + j] = bf2f(vv[j]);
    }
  }
  float w16[16], u16[16], s[16];
  const size_t sbase = (((size_t)h * NCHUNK + c) * HS_DIM + kg * 16) * HS_DIM + vcol;
#pragma unroll
  for (int j = 0; j < 16; ++j) {
    int kidx = kg * 16 + j;
    w16[j] = expf(-expf(decay[h * HS_DIM + kidx]));
    u16[j] = faaaa[h * HS_DIM + kidx];
    s[j] = Sbuf[sbase + (size_t)j * HS_DIM];
  }
  __syncthreads();
  for (int t = 0; t < CHUNK; ++t) {
    const float vt = vs[t][vcol];
    const float4* kp = (const float4*)&ks[t][kg * 16];
    const float4* rp = (const float4*)&rs[t][kg * 16];
    float acc = 0.f, ruk = 0.f;
#pragma unroll
    for (int q = 0; q < 4; ++q) {
      float4 k4 = kp[q], r4 = rp[q];
      acc = __builtin_fmaf(r4.x, s[q * 4 + 0], acc);
      ruk = __builtin_fmaf(r4.x * u16[q * 4 + 0], k4.x, ruk);
      s[q * 4 + 0] = __builtin_fmaf(s[q * 4 + 0], w16[q * 4 + 0], k4.x * vt);
      acc = __builtin_fmaf(r4.y, s[q * 4 + 1], acc);
      ruk = __builtin_fmaf(r4.y * u16[q * 4 + 1], k4.y, ruk);
      s[q * 4 + 1] = __builtin_fmaf(s[q * 4 + 1], w16[q * 4 + 1], k4.y * vt);
      acc = __builtin_fmaf(r4.z, s[q * 4 + 2], acc);
      ruk = __builtin_fmaf(r4.z * u16[q * 4 + 2], k4.z, ruk);
      s[q * 4 + 2] = __builtin_fmaf(s[q * 4 + 2], w16[q * 4 + 2], k4.z * vt);
      acc = __builtin_fmaf(r4.w, s[q * 4 + 3], acc);
      ruk = __builtin_fmaf(r4.w * u16[q * 4 + 3], k4.w, ruk);
      s[q * 4 + 3] = __builtin_fmaf(s[q * 4 + 3], w16[q * 4 + 3], k4.w * vt);
    }
    float part = __builtin_fmaf(ruk, vt, acc);
    part += __shfl_xor(part, 1);
    part += __shfl_xor(part, 2);
    if (kg == 0) os[t][vcol] = part;
  }
  __syncthreads();
  const int tt = tid >> 2, q = tid & 3;
  float z16[16];
  float sm = 0.f, sq2 = 0.f;
#pragma unroll
  for (int j = 0; j < 16; ++j) {
    float z = os[tt][q * 16 + j] * 0.125f;
    z16[j] = z;
    sm += z;
    sq2 = __builtin_fmaf(z, z, sq2);
  }
  sm += __shfl_xor(sm, 1); sq2 += __shfl_xor(sq2, 1);
  sm += __shfl_xor(sm, 2); sq2 += __shfl_xor(sq2, 2);
  const float mean = sm * (1.f / HS_DIM);
  const float inv = rsqrtf(sq2 * (1.f / HS_DIM) - mean * mean + 1e-5f);
  const int ccol = h * HS_DIM + q * 16;
  const size_t obase = (size_t)(c * CHUNK + tt) * C_DIM + ccol;
  float gwv[16], gbv[16];
  *(float4*)&gwv[0] = *(const float4*)(gw + ccol);
  *(float4*)&gwv[4] = *(const float4*)(gw + ccol + 4);
  *(float4*)&gwv[8] = *(const float4*)(gw + ccol + 8);
  *(float4*)&gwv[12] = *(const float4*)(gw + ccol + 12);
  *(float4*)&gbv[0] = *(const float4*)(gb + ccol);
  *(float4*)&gbv[4] = *(const float4*)(gb + ccol + 4);
  *(float4*)&gbv[8] = *(const float4*)(gb + ccol + 8);
  *(float4*)&gbv[12] = *(const float4*)(gb + ccol + 12);
  short8 gp0 = *(const short8*)(gpre + obase);
  short8 gp1 = *(const short8*)(gpre + obase + 8);
  short8 o0, o1;
#pragma unroll
  for (int j = 0; j < 8; ++j) {
    const float g = bf2f(gp0[j]);
    const float sig = 1.f / (1.f + __expf(-g));
    const float val = (z16[j] - mean) * inv * gwv[j] + gbv[j];
    o0[j] = (short)f2bf(val * (g * sig));
  }
#pragma unroll
  for (int j = 0; j < 8; ++j) {
    const float g = bf2f(gp1[j]);
    const float sig = 1.f / (1.f + __expf(-g));
    const float val = (z16[8 + j] - mean) * inv * gwv[8 + j] + gbv[8 + j];
    o1[j] = (short)f2bf(val * (g * sig));
  }
  *(short8*)(zg + obase) = o0;
  *(short8*)(zg + obase + 8) = o1;
}

// ===== bf16-A x f32-B GEMM, BM=128 BN=128 BK=32, wave tile 64x64, pair-barrier =====
struct GemmBatch {
  const unsigned short* A[4];
  const float* B[4];
  void* C[4];
};

template <int EPI, int SPLITK>
__global__ __launch_bounds__(256) void gemm128(GemmBatch gb, int M, int N, int K,
                                               float* __restrict__ P) {
  const int nx = gridDim.x, ny = gridDim.y;
  const int nwg = nx * ny * gridDim.z;
  const int h = (blockIdx.z * ny + blockIdx.y) * nx + blockIdx.x;
  const int chunkw = nwg >> 3;
  const int wrk = (h & 7) * chunkw + (h >> 3);
  const int zz = wrk / (nx * ny);
  const int rem = wrk - zz * (nx * ny);
  const int by = rem % ny;
  const int bx = rem / ny;

  const int s = zz % SPLITK, zb = zz / SPLITK;
  const int Ks = K / SPLITK;
  const int k0 = s * Ks;
  const unsigned short* __restrict__ A = gb.A[zb];
  const float* __restrict__ B = gb.B[zb];
  const int m0 = by * 128, n0 = bx * 128;

  __shared__ unsigned short As[4][128 * 32];
  __shared__ unsigned short Bs[4][128 * 32];

  const int tid = threadIdx.x;
  const int l = tid & 63;
  const int w = tid >> 6;
  const int wm = w >> 1, wn = w & 1;
  const int lrow = l & 15;
  const size_t Kb = (size_t)K * 2;

  const int srow = w * 16 + (l >> 2);
  const int kslot = ((l & 3) ^ ((l >> 3) & 3)) * 16;
  const char* Agl = (const char*)A + (size_t)(m0 + srow) * Kb + kslot;
  const int brl = w * 32 + (l >> 2);
  const int bcol = (l & 3) * 8;

  f32x4 acc[4][4];
#pragma unroll
  for (int m = 0; m < 4; ++m)
#pragma unroll
    for (int n = 0; n < 4; ++n) acc[m][n] = (f32x4){0.f, 0.f, 0.f, 0.f};

#define STGA(buf, kk)                                                        \
  {                                                                          \
    const size_t kb2 = (size_t)(kk) * 2;                                     \
    gl_lds16(Agl + kb2, (char*)&As[buf][0] + w * 1024);                      \
    gl_lds16(Agl + 64 * Kb + kb2, (char*)&As[buf][0] + 4096 + w * 1024);     \
  }

#define LDB(kk, lo0, hi0, lo1, hi1)                                          \
  {                                                                          \
    const float* p0 = B + (size_t)(n0 + brl) * K + (kk) + bcol;              \
    const float* p1 = B + (size_t)(n0 + brl + 16) * K + (kk) + bcol;         \
    lo0 = *(const f32x4*)p0; hi0 = *(const f32x4*)(p0 + 4);                  \
    lo1 = *(const f32x4*)p1; hi1 = *(const f32x4*)(p1 + 4);                  \
  }

#define WRB(buf, lo0, hi0, lo1, hi1)                                         \
  {                                                                          \
    u32x4 q0, q1;                                                            \
    q0[0] = cvtpk(lo0[0], lo0[1]); q0[1] = cvtpk(lo0[2], lo0[3]);            \
    q0[2] = cvtpk(hi0[0], hi0[1]); q0[3] = cvtpk(hi0[2], hi0[3]);            \
    q1[0] = cvtpk(lo1[0], lo1[1]); q1[1] = cvtpk(lo1[2], lo1[3]);            \
    q1[2] = cvtpk(hi1[0], hi1[1]); q1[3] = cvtpk(hi1[2], hi1[3]);            \
    const int sl0 = (l & 3) ^ ((brl >> 1) & 3);                              \
    *(u32x4*)((char*)&Bs[buf][0] + brl * 64 + sl0 * 16) = q0;                \
    *(u32x4*)((char*)&Bs[buf][0] + (brl + 16) * 64 + sl0 * 16) = q1;         \
  }

#define COMPUTE(tt)                                                          \
  {                                                                          \
    const char* Ab = (const char*)&As[(tt) & 3][0];                          \
    const char* Bb = (const char*)&Bs[(tt) & 3][0];                          \
    const int kb = (l >> 4) * 16;                                            \
    const int kbs = kb ^ (((lrow >> 1) & 3) << 4);                           \
    short8 af[4], bfr[4];                                                    \
    _Pragma("unroll") for (int m = 0; m < 4; ++m) {                          \
      const int row = wm * 64 + m * 16 + lrow;                               \
      af[m] = *(const short8*)(Ab + row * 64 + kbs);                         \
    }                                                                        \
    _Pragma("unroll") for (int n = 0; n < 4; ++n) {                          \
      const int row = wn * 64 + n * 16 + lrow;                               \
      bfr[n] = *(const short8*)(Bb + row * 64 + kbs);                        \
    }                                                                        \
    _Pragma("unroll") for (int m = 0; m < 4; ++m)                            \
        _Pragma("unroll") for (int n = 0; n < 4; ++n) acc[m][n] =            \
            __builtin_amdgcn_mfma_f32_16x16x32_bf16(af[m], bfr[n],           \
                                                    acc[m][n], 0, 0, 0);     \
  }

  const int nt = Ks / 32;
  f32x4 bA0, bA1, bA2, bA3, bB0, bB1, bB2, bB3;
  LDB(k0, bA0, bA1, bA2, bA3);
  LDB(k0 + 32, bB0, bB1, bB2, bB3);
  STGA(0, k0);
  STGA(1, k0 + 32);
  WRB(0, bA0, bA1, bA2, bA3);
  WRB(1, bB0, bB1, bB2, bB3);

  for (int t = 0; t < nt; t += 2) {
    asm volatile("s_waitcnt vmcnt(0) lgkmcnt(0)" ::: "memory");
    __builtin_amdgcn_sched_barrier(0);
    __builtin_amdgcn_s_barrier();
    __builtin_amdgcn_sched_barrier(0);
    const bool more = (t + 2 < nt);
    if (more) {
      LDB(k0 + (t + 2) * 32, bA0, bA1, bA2, bA3);
      LDB(k0 + (t + 3) * 32, bB0, bB1, bB2, bB3);
      STGA((t + 2) & 3, k0 + (t + 2) * 32);
      STGA((t + 3) & 3, k0 + (t + 3) * 32);
    }
    COMPUTE(t);
    if (more) {
      WRB((t + 2) & 3, bA0, bA1, bA2, bA3);
      WRB((t + 3) & 3, bB0, bB1, bB2, bB3);
    }
    COMPUTE(t + 1);
  }
#undef STGA
#undef LDB
#undef WRB
#undef COMPUTE

  float* Co;
  if (SPLITK > 1)
    Co = (s == 0) ? (float*)gb.C[zb] : P + (size_t)(s - 1) * M * N;
  else
    Co = (float*)gb.C[zb];

#pragma unroll
  for (int m = 0; m < 4; ++m) {
#pragma unroll
    for (int n = 0; n < 4; ++n) {
#pragma unroll
      for (int j = 0; j < 4; ++j) {
        const int row = m0 + wm * 64 + m * 16 + ((l >> 4) << 2) + j;
        const int col = n0 + wn * 64 + n * 16 + lrow;
        const size_t idx = (size_t)row * N + col;
        const float v = acc[m][n][j];
        if (EPI == 2 && SPLITK == 1) {
          float tpos = v > 0.f ? v : 0.f;
          ((unsigned short*)gb.C[zb])[idx] = f2bf(tpos * tpos);
        } else if (EPI == 3 && SPLITK == 1) {
          ((unsigned short*)gb.C[zb])[idx] = f2bf(v);
        } else {
          Co[idx] = v;
        }
      }
    }
  }
}

// ===== 256x256 8-wave GEMM, BK=64, double-buffer, 1 barrier per K=64 =====
// bf16-A via global_load_lds (pre-swizzled source); f32-B reg-staged + cvtpk.
// Swizzle: slot(16B) ^= row&7 on both write-source and read. C = bf16 raw.
struct Gemm256Batch {
  const unsigned short* A[4];
  const float* B[4];
  unsigned short* C[4];
};

template <int SPLITK>
__global__ __launch_bounds__(512) void gemm256(Gemm256Batch gb, int M, int N, int K) {
  const int nx = gridDim.x, ny = gridDim.y;
  const int nwg = nx * ny * gridDim.z;
  const int hh = (blockIdx.z * ny + blockIdx.y) * nx + blockIdx.x;
  const int chunkw = nwg >> 3;
  const int wrk = (hh & 7) * chunkw + (hh >> 3);
  const int zz = wrk / (nx * ny);
  const int rem = wrk - zz * (nx * ny);
  const int by = rem % ny;
  const int bx = rem / ny;
  const int s = zz % SPLITK, zb = zz / SPLITK;
  const int Ks = K / SPLITK, k0 = s * Ks;
  const unsigned short* __restrict__ A = gb.A[zb];
  const float* __restrict__ B = gb.B[zb];
  const int m0 = by * 256, n0 = bx * 256;

  __shared__ unsigned short As[2][256 * 64];  // 32 KB each
  __shared__ unsigned short Bs[2][256 * 64];

  const int tid = threadIdx.x;
  const int l = tid & 63;
  const int w = tid >> 6;   // 0..7
  const int wm = w >> 2;    // 0..1
  const int wn = w & 3;     // 0..3
  const int lrow = l & 15;
  const size_t Kb = (size_t)K * 2;

  // A staging: issue i covers LDS rows [i*64 + w*8, +8); lane l -> row +(l>>3), slot l&7
  const int arow = w * 8 + (l >> 3);
  const int aslot = ((l & 7) ^ ((l >> 3) & 7)) * 16;
  const char* Agl = (const char*)A + (size_t)(m0 + arow) * Kb + aslot;

  // B reg staging: lane covers rows brow + 8j (j=0..3), slot l&7
  const int brow = w * 32 + (l >> 3);
  const int bslot = l & 7;
  const int bgcol = (bslot ^ ((l >> 3) & 7)) * 8;  // f32 col

  f32x4 acc[8][4];
#pragma unroll
  for (int m = 0; m < 8; ++m)
#pragma unroll
    for (int n = 0; n < 4; ++n) acc[m][n] = (f32x4){0.f, 0.f, 0.f, 0.f};

  f32x4 br[8];

#define STGA6(buf, kk)                                                       \
  {                                                                          \
    const size_t kb2 = (size_t)(kk) * 2;                                     \
    gl_lds16(Agl + kb2, (char*)&As[buf][0] + w * 1024);                      \
    gl_lds16(Agl + 64 * Kb + kb2, (char*)&As[buf][0] + 8192 + w * 1024);     \
    gl_lds16(Agl + 128 * Kb + kb2, (char*)&As[buf][0] + 16384 + w * 1024);   \
    gl_lds16(Agl + 192 * Kb + kb2, (char*)&As[buf][0] + 24576 + w * 1024);   \
  }

#define LDB6(kk)                                                             \
  {                                                                          \
    _Pragma("unroll") for (int j = 0; j < 4; ++j) {                          \
      const float* p = B + (size_t)(n0 + brow + 8 * j) * K + (kk) + bgcol;   \
      br[2 * j] = *(const f32x4*)p;                                          \
      br[2 * j + 1] = *(const f32x4*)(p + 4);                                \
    }                                                                        \
  }

#define WRB6(buf)                                                            \
  {                                                                          \
    _Pragma("unroll") for (int j = 0; j < 4; ++j) {                          \
      u32x4 qq;                                                              \
      qq[0] = cvtpk(br[2 * j][0], br[2 * j][1]);                             \
      qq[1] = cvtpk(br[2 * j][2], br[2 * j][3]);                             \
      qq[2] = cvtpk(br[2 * j + 1][0], br[2 * j + 1][1]);                     \
      qq[3] = cvtpk(br[2 * j + 1][2], br[2 * j + 1][3]);                     \
      *(u32x4*)((char*)&Bs[buf][0] + (brow + 8 * j) * 128 + bslot * 16) = qq;\
    }                                                                        \
  }

#define COMPUTE6(buf)                                                        \
  {                                                                          \
    const char* Ab = (const char*)&As[buf][0];                               \
    const char* Bb = (const char*)&Bs[buf][0];                               \
    _Pragma("unroll") for (int ks = 0; ks < 2; ++ks) {                       \
      const int kb = ks * 64 + (l >> 4) * 16;                                \
      short8 af[8], bfr[4];                                                  \
      _Pragma("unroll") for (int m = 0; m < 8; ++m) {                        \
        const int row = wm * 128 + m * 16 + lrow;                            \
        af[m] = *(const short8*)(Ab + row * 128 + (kb ^ ((row & 7) << 4)));  \
      }                                                                      \
      _Pragma("unroll") for (int n = 0; n < 4; ++n) {                        \
        const int row = wn * 64 + n * 16 + lrow;                             \
        bfr[n] = *(const short8*)(Bb + row * 128 + (kb ^ ((row & 7) << 4))); \
      }                                                                      \
      _Pragma("unroll") for (int m = 0; m < 8; ++m)                          \
          _Pragma("unroll") for (int n = 0; n < 4; ++n) acc[m][n] =          \
              __builtin_amdgcn_mfma_f32_16x16x32_bf16(af[m], bfr[n],         \
                                                      acc[m][n], 0, 0, 0);   \
    }                                                                        \
  }

  const int nt = Ks / 64;
  LDB6(k0);
  STGA6(0, k0);
  WRB6(0);

  for (int t = 0; t < nt; ++t) {
    asm volatile("s_waitcnt vmcnt(0) lgkmcnt(0)" ::: "memory");
    __builtin_amdgcn_sched_barrier(0);
    __builtin_amdgcn_s_barrier();
    __builtin_amdgcn_sched_barrier(0);
    const bool more = (t + 1 < nt);
    if (more) {
      LDB6(k0 + (t + 1) * 64);
      STGA6((t + 1) & 1, k0 + (t + 1) * 64);
    }
    __builtin_amdgcn_s_setprio(1);
    COMPUTE6(t & 1);
    __builtin_amdgcn_s_setprio(0);
    if (more) WRB6((t + 1) & 1);
  }
#undef STGA6
#undef LDB6
#undef WRB6
#undef COMPUTE6

  unsigned short* C = gb.C[zb];
  // SPLITK handled by caller only when SPLITK==1 writes; here: for SPLITK>1 we
  // accumulate via separate halves of K handled by different z — but gemm4 uses
  // full-K per split via atomic-free two-pass? No: SPLITK==2 splits K; partials
  // must be summed. We instead require SPLITK==2 with bf16 out => use f32 add:
  // To keep it simple and exact, split 0 writes f32 partial to Ptmp? Avoid:
  // gemm4 tolerates summation order; we do: each split writes its partial to
  // a DISTINCT f32 buffer passed via C aliasing is complex — so gemm256 is
  // used ONLY with SPLITK==1 semantics per launch (caller passes pre-split K).
#pragma unroll
  for (int m = 0; m < 8; ++m) {
#pragma unroll
    for (int n = 0; n < 4; ++n) {
#pragma unroll
      for (int j = 0; j < 4; ++j) {
        const int row = m0 + wm * 128 + m * 16 + ((l >> 4) << 2) + j;
        const int col = n0 + wn * 64 + n * 16 + lrow;
        const size_t idx = (size_t)row * N + col;
        C[idx] = f2bf(acc[m][n][j]);
      }
    }
  }
}

// ------ final reduce: out = xnewF + sig(s1+Q0+Q1+Q2) * (C + P0 + P1 + P2) ------
__global__ __launch_bounds__(256) void reduce_final(float* __restrict__ C,
                                                    const float* __restrict__ P,
                                                    const float* __restrict__ E0,
                                                    const float* __restrict__ E1,
                                                    const float* __restrict__ Q,
                                                    size_t n4) {
  for (size_t i = (size_t)blockIdx.x * 256 + threadIdx.x; i < n4;
       i += (size_t)gridDim.x * 256) {
    float4 c = ((const float4*)C)[i];
    float4 p = ((const float4*)P)[i];
    float4 p1 = ((const float4*)P)[i + n4];
    float4 p2 = ((const float4*)P)[i + 2 * n4];
    float4 e0 = ((const float4*)E0)[i];
    float4 e1 = ((const float4*)E1)[i];
    float4 q0 = ((const float4*)Q)[i];
    float4 q1 = ((const float4*)Q)[i + n4];
    float4 q2 = ((const float4*)Q)[i + 2 * n4];
    const float sx = e0.x + q0.x + q1.x + q2.x;
    const float sy = e0.y + q0.y + q1.y + q2.y;
    const float sz = e0.z + q0.z + q1.z + q2.z;
    const float sw = e0.w + q0.w + q1.w + q2.w;
    c.x = e1.x + (1.f / (1.f + __expf(-sx))) * (c.x + p.x + p1.x + p2.x);
    c.y = e1.y + (1.f / (1.f + __expf(-sy))) * (c.y + p.y + p1.y + p2.y);
    c.z = e1.z + (1.f / (1.f + __expf(-sz))) * (c.z + p.z + p1.z + p2.z);
    c.w = e1.w + (1.f / (1.f + __expf(-sw))) * (c.w + p.w + p1.w + p2.w);
    ((float4*)C)[i] = c;
  }
}

extern "C" void kernel_launch(void* const* d_in, const int* in_sizes, int n_in,
                              void* d_out, int out_size, void* d_ws, size_t ws_size,
                              hipStream_t stream) {
  (void)in_sizes; (void)n_in; (void)out_size; (void)ws_size;
  const float* x         = (const float*)d_in[0];
  const float* att_shift = (const float*)d_in[1];
  const float* wkv_state = (const float*)d_in[2];
  const float* ffn_shift = (const float*)d_in[3];
  const float* ln1_w = (const float*)d_in[4];
  const float* ln1_b = (const float*)d_in[5];
  const float* ln2_w = (const float*)d_in[6];
  const float* ln2_b = (const float*)d_in[7];
  const float* tm_k = (const float*)d_in[8];
  const float* tm_v = (const float*)d_in[9];
  const float* tm_r = (const float*)d_in[10];
  const float* tm_g = (const float*)d_in[11];
  const float* time_decay = (const float*)d_in[12];
  const float* time_faaaa = (const float*)d_in[13];
  const float* Wr = (const float*)d_in[14];
  const float* Wk = (const float*)d_in[15];
  const float* Wv = (const float*)d_in[16];
  const float* Wo = (const float*)d_in[17];
  const float* Wg = (const float*)d_in[18];
  const float* gn_w = (const float*)d_in[19];
  const float* gn_b = (const float*)d_in[20];
  const float* cm_k = (const float*)d_in[21];
  const float* cm_r = (const float*)d_in[22];
  const float* Wck = (const float*)d_in[23];
  const float* Wcr = (const float*)d_in[24];
  const float* Wcv = (const float*)d_in[25];
  float* out = (float*)d_out;

  char* act = (char*)d_ws;

  const size_t R = (size_t)T_LEN * C_DIM;        // elements
  const size_t RF = R * 4;                       // f32 bytes
  const size_t RB = R * 2;                       // bf16 bytes
  float*          x1   = (float*)(act);                        // Pgv
  unsigned short* xr_b = (unsigned short*)(act + RF);          // Abuf; Pgv tail
  unsigned short* xk_b = (unsigned short*)(act + RF + RB);
  unsigned short* xv_b = (unsigned short*)(act + RF + 2 * RB); // Sbuf
  unsigned short* xg_b = (unsigned short*)(act + RF + 3 * RB);
  float*          rb   = (float*)(act + RF + 4 * RB);
  float*          kb   = (float*)(act + 2 * RF + 4 * RB);      // k (bf16) + xk2,xr2
  float*          vb   = (float*)(act + 3 * RF + 4 * RB);      // v (bf16); kk_b spans vb+gpre
  float*          gpre = (float*)(act + 4 * RF + 4 * RB);      // gpre (bf16)
  unsigned short* zg_b = (unsigned short*)(act + 5 * RF + 4 * RB);
  float*          xnew = (float*)(act + 5 * RF + 5 * RB);      // go split0 partial
  float*          s1   = (float*)(act + 6 * RF + 5 * RB);
  float*          xnewF = (float*)(act + 7 * RF + 5 * RB);     // final xnew
  float*          Pgo_m = (float*)(act + 8 * RF + 5 * RB);     // go splits 1-3 (3*RF)
  float*          Pgr_m = (float*)(act + 11 * RF + 5 * RB);    // gr splits 1-3 (3*RF)
  // aliases
  float*          Abuf  = (float*)xr_b;
  float*          Sbuf  = (float*)xv_b;
  unsigned short* rb_b  = (unsigned short*)rb;
  unsigned short* kb_b  = (unsigned short*)kb;
  unsigned short* vb_b  = (unsigned short*)vb;
  unsigned short* gp_b  = (unsigned short*)gpre;
  unsigned short* xk2_b = (unsigned short*)kb;                 // kb dead after wkv
  unsigned short* xr2_b = (unsigned short*)((char*)kb + RB);
  unsigned short* kk_b  = (unsigned short*)vb;                 // spans vb+gpre
  float*          Pgv   = x1;            // 25.2 MB (x1 + xr..xg), dead during Wcv GEMM

  dim3 blk(256);
  const size_t n4 = R / 4;

  // --- TimeMix ---
  ln_mix_att<<<T_LEN, blk, 0, stream>>>(x, att_shift, ln1_w, ln1_b,
                                        tm_r, tm_k, tm_v, tm_g,
                                        xr_b, xk_b, xv_b, xg_b);
  // 256x256 8-wave GEMM for the r/k/v/g batch: grid 8x4x4 = 128 blocks of 512 thr
  Gemm256Batch g4 = {};
  g4.A[0] = xr_b; g4.B[0] = Wr; g4.C[0] = rb_b;
  g4.A[1] = xk_b; g4.B[1] = Wk; g4.C[1] = kb_b;
  g4.A[2] = xv_b; g4.B[2] = Wv; g4.C[2] = vb_b;
  g4.A[3] = xg_b; g4.B[3] = Wg; g4.C[3] = gp_b;
  gemm256<1><<<dim3(8, 4, 4), dim3(512), 0, stream>>>(g4, T_LEN, C_DIM, C_DIM);

  // chunk-parallel WKV scan (bf16 inputs, f32 state) + fused GroupNorm/silu
  wkv_chunk_sum<<<dim3(NCHUNK, H_NUM), blk, 0, stream>>>(kb_b, vb_b, time_decay, Abuf);
  wkv_chain<<<H_NUM, blk, 0, stream>>>(Abuf, wkv_state, time_decay, Sbuf);
  wkv_chunk_out_gn<<<dim3(NCHUNK, H_NUM), blk, 0, stream>>>(
      kb_b, vb_b, rb_b, time_decay, time_faaaa, Sbuf, gp_b, gn_w, gn_b, zg_b);

  GemmBatch go = {};
  go.A[0] = zg_b; go.B[0] = Wo; go.C[0] = xnew;
  gemm128<0, 4><<<dim3(16, 8, 4), blk, 0, stream>>>(go, T_LEN, C_DIM, C_DIM, Pgo_m);

  // --- ChannelMix (xnew composed inline from 4 partials; writes final xnew + mixes) ---
  ln_mix_cm_f<<<T_LEN, blk, 0, stream>>>(xnew, Pgo_m, x, ffn_shift, ln2_w, ln2_b,
                                         cm_k, cm_r, xnewF, xk2_b, xr2_b);

  GemmBatch gk = {};
  gk.A[0] = xk2_b; gk.B[0] = Wck; gk.C[0] = kk_b;
  gemm128<2, 1><<<dim3(56, 8, 1), blk, 0, stream>>>(gk, T_LEN, FF_DIM, C_DIM, nullptr);

  GemmBatch gr = {};
  gr.A[0] = xr2_b; gr.B[0] = Wcr; gr.C[0] = s1;
  gemm128<0, 4><<<dim3(16, 8, 4), blk, 0, stream>>>(gr, T_LEN, C_DIM, C_DIM, Pgr_m);

  GemmBatch gv = {};
  gv.A[0] = kk_b; gv.B[0] = Wcv; gv.C[0] = out;
  gemm128<0, 4><<<dim3(16, 8, 4), blk, 0, stream>>>(gv, T_LEN, C_DIM, FF_DIM, Pgv);
  reduce_final<<<2048, blk, 0, stream>>>(out, Pgv, s1, xnewF, Pgr_m, n4);
}

// Round 19
// 320.593 us; speedup vs baseline: 1.1070x; 1.1070x over previous
//
#include <hip/hip_runtime.h>

#define T_LEN 1024
#define C_DIM 2048
#define H_NUM 32
#define HS_DIM 64
#define FF_DIM 7168
#define CHUNK 64
#define NCHUNK (T_LEN / CHUNK)

typedef __attribute__((ext_vector_type(4))) float f32x4;
typedef __attribute__((ext_vector_type(8))) short short8;
typedef __attribute__((ext_vector_type(4))) unsigned int u32x4;

__device__ __forceinline__ unsigned short f2bf(float f) {
  unsigned int u = __float_as_uint(f);
  unsigned int r = (u + 0x7FFFu + ((u >> 16) & 1u)) >> 16;
  return (unsigned short)r;
}

__device__ __forceinline__ float bf2f(short s) {
  return __uint_as_float(((unsigned int)(unsigned short)s) << 16);
}

// HW packed f32->bf16 (RNE)
__device__ __forceinline__ unsigned int cvtpk(float a, float b) {
  unsigned int r;
  asm("v_cvt_pk_bf16_f32 %0, %1, %2" : "=v"(r) : "v"(a), "v"(b));
  return r;
}

__device__ __forceinline__ short8 pack_bf8(float4 a, float4 b) {
  short8 o;
  o[0] = (short)f2bf(a.x); o[1] = (short)f2bf(a.y);
  o[2] = (short)f2bf(a.z); o[3] = (short)f2bf(a.w);
  o[4] = (short)f2bf(b.x); o[5] = (short)f2bf(b.y);
  o[6] = (short)f2bf(b.z); o[7] = (short)f2bf(b.w);
  return o;
}

__device__ __forceinline__ void gl_lds16(const void* g, void* l) {
  __builtin_amdgcn_global_load_lds(
      (const __attribute__((address_space(1))) unsigned int*)g,
      (__attribute__((address_space(3))) unsigned int*)l, 16, 0, 0);
}

// ---------------- fused LN + TimeMix token-shift (4 bf16 outputs) ----------------
__global__ __launch_bounds__(256) void ln_mix_att(const float* __restrict__ x,
                                                  const float* __restrict__ shift,
                                                  const float* __restrict__ lw,
                                                  const float* __restrict__ lb,
                                                  const float* __restrict__ mr,
                                                  const float* __restrict__ mk,
                                                  const float* __restrict__ mv,
                                                  const float* __restrict__ mg,
                                                  unsigned short* __restrict__ xr,
                                                  unsigned short* __restrict__ xk,
                                                  unsigned short* __restrict__ xv,
                                                  unsigned short* __restrict__ xg) {
  const int t = blockIdx.x;
  const int tid = threadIdx.x;
  const int c0 = tid * 8;
  const float* xrow = x + (size_t)t * C_DIM;
  float cur[8], prv[8];
  *(float4*)&cur[0] = *(const float4*)(xrow + c0);
  *(float4*)&cur[4] = *(const float4*)(xrow + c0 + 4);
  const bool hp = (t > 0);
  const float* prow = hp ? (xrow - C_DIM) : (shift + 0);
  *(float4*)&prv[0] = *(const float4*)(prow + c0);
  *(float4*)&prv[4] = *(const float4*)(prow + c0 + 4);
  float s0 = 0.f, q0 = 0.f, s1 = 0.f, q1 = 0.f;
#pragma unroll
  for (int i = 0; i < 8; ++i) {
    s0 += cur[i]; q0 = __builtin_fmaf(cur[i], cur[i], q0);
    s1 += prv[i]; q1 = __builtin_fmaf(prv[i], prv[i], q1);
  }
#pragma unroll
  for (int o = 1; o < 64; o <<= 1) {
    s0 += __shfl_xor(s0, o); q0 += __shfl_xor(q0, o);
    s1 += __shfl_xor(s1, o); q1 += __shfl_xor(q1, o);
  }
  __shared__ float red[4][4];
  const int wave = tid >> 6, lane = tid & 63;
  if (lane == 0) { red[wave][0] = s0; red[wave][1] = q0; red[wave][2] = s1; red[wave][3] = q1; }
  __syncthreads();
  s0 = red[0][0] + red[1][0] + red[2][0] + red[3][0];
  q0 = red[0][1] + red[1][1] + red[2][1] + red[3][1];
  s1 = red[0][2] + red[1][2] + red[2][2] + red[3][2];
  q1 = red[0][3] + red[1][3] + red[2][3] + red[3][3];
  const float mean0 = s0 * (1.f / C_DIM);
  const float inv0 = rsqrtf(q0 * (1.f / C_DIM) - mean0 * mean0 + 1e-5f);
  const float mean1 = s1 * (1.f / C_DIM);
  const float inv1 = rsqrtf(q1 * (1.f / C_DIM) - mean1 * mean1 + 1e-5f);
  float w8[8], b8[8];
  *(float4*)&w8[0] = *(const float4*)(lw + c0);
  *(float4*)&w8[4] = *(const float4*)(lw + c0 + 4);
  *(float4*)&b8[0] = *(const float4*)(lb + c0);
  *(float4*)&b8[4] = *(const float4*)(lb + c0 + 4);
  float curn[8], prvn[8];
#pragma unroll
  for (int i = 0; i < 8; ++i) {
    curn[i] = (cur[i] - mean0) * inv0 * w8[i] + b8[i];
    prvn[i] = hp ? ((prv[i] - mean1) * inv1 * w8[i] + b8[i]) : prv[i];
  }
  const size_t idx = (size_t)t * C_DIM + c0;
  const float* mixp[4] = {mr, mk, mv, mg};
  unsigned short* dst[4] = {xr, xk, xv, xg};
#pragma unroll
  for (int which = 0; which < 4; ++which) {
    const float* m = mixp[which];
    float o[8];
#pragma unroll
    for (int i = 0; i < 8; ++i) {
      float a = m[c0 + i];
      o[i] = curn[i] * a + prvn[i] * (1.f - a);
    }
    *(short8*)(dst[which] + idx) = pack_bf8(*(float4*)&o[0], *(float4*)&o[4]);
  }
}

// ------- fused (xnew = goC + P0+P1+P2 + x) + LN2 + ChannelMix mixes; writes xnew -------
__global__ __launch_bounds__(256) void ln_mix_cm_f(const float* __restrict__ goC,
                                                   const float* __restrict__ P,
                                                   const float* __restrict__ x,
                                                   const float* __restrict__ shift,
                                                   const float* __restrict__ lw,
                                                   const float* __restrict__ lb,
                                                   const float* __restrict__ mk,
                                                   const float* __restrict__ mr,
                                                   float* __restrict__ xnewF,
                                                   unsigned short* __restrict__ xk2,
                                                   unsigned short* __restrict__ xr2) {
  const int t = blockIdx.x;
  const int tid = threadIdx.x;
  const int c0 = tid * 8;
  const size_t rc = (size_t)t * C_DIM + c0;
  const size_t R = (size_t)T_LEN * C_DIM;
  float cur[8], prv[8];
  {
    float4 g1 = *(const float4*)(goC + rc), g2 = *(const float4*)(goC + rc + 4);
    float4 p1 = *(const float4*)(P + rc), p2 = *(const float4*)(P + rc + 4);
    float4 q1 = *(const float4*)(P + R + rc), q2 = *(const float4*)(P + R + rc + 4);
    float4 r1 = *(const float4*)(P + 2 * R + rc), r2 = *(const float4*)(P + 2 * R + rc + 4);
    float4 x1 = *(const float4*)(x + rc), x2 = *(const float4*)(x + rc + 4);
    cur[0] = g1.x + p1.x + q1.x + r1.x + x1.x;
    cur[1] = g1.y + p1.y + q1.y + r1.y + x1.y;
    cur[2] = g1.z + p1.z + q1.z + r1.z + x1.z;
    cur[3] = g1.w + p1.w + q1.w + r1.w + x1.w;
    cur[4] = g2.x + p2.x + q2.x + r2.x + x2.x;
    cur[5] = g2.y + p2.y + q2.y + r2.y + x2.y;
    cur[6] = g2.z + p2.z + q2.z + r2.z + x2.z;
    cur[7] = g2.w + p2.w + q2.w + r2.w + x2.w;
  }
  const bool hp = (t > 0);
  if (hp) {
    const size_t rp = rc - C_DIM;
    float4 g1 = *(const float4*)(goC + rp), g2 = *(const float4*)(goC + rp + 4);
    float4 p1 = *(const float4*)(P + rp), p2 = *(const float4*)(P + rp + 4);
    float4 q1 = *(const float4*)(P + R + rp), q2 = *(const float4*)(P + R + rp + 4);
    float4 r1 = *(const float4*)(P + 2 * R + rp), r2 = *(const float4*)(P + 2 * R + rp + 4);
    float4 x1 = *(const float4*)(x + rp), x2 = *(const float4*)(x + rp + 4);
    prv[0] = g1.x + p1.x + q1.x + r1.x + x1.x;
    prv[1] = g1.y + p1.y + q1.y + r1.y + x1.y;
    prv[2] = g1.z + p1.z + q1.z + r1.z + x1.z;
    prv[3] = g1.w + p1.w + q1.w + r1.w + x1.w;
    prv[4] = g2.x + p2.x + q2.x + r2.x + x2.x;
    prv[5] = g2.y + p2.y + q2.y + r2.y + x2.y;
    prv[6] = g2.z + p2.z + q2.z + r2.z + x2.z;
    prv[7] = g2.w + p2.w + q2.w + r2.w + x2.w;
  } else {
    *(float4*)&prv[0] = *(const float4*)(shift + c0);
    *(float4*)&prv[4] = *(const float4*)(shift + c0 + 4);
  }
  *(float4*)(xnewF + rc) = *(float4*)&cur[0];
  *(float4*)(xnewF + rc + 4) = *(float4*)&cur[4];

  float s0 = 0.f, q0 = 0.f, s1 = 0.f, q1 = 0.f;
#pragma unroll
  for (int i = 0; i < 8; ++i) {
    s0 += cur[i]; q0 = __builtin_fmaf(cur[i], cur[i], q0);
    s1 += prv[i]; q1 = __builtin_fmaf(prv[i], prv[i], q1);
  }
#pragma unroll
  for (int o = 1; o < 64; o <<= 1) {
    s0 += __shfl_xor(s0, o); q0 += __shfl_xor(q0, o);
    s1 += __shfl_xor(s1, o); q1 += __shfl_xor(q1, o);
  }
  __shared__ float red[4][4];
  const int wave = tid >> 6, lane = tid & 63;
  if (lane == 0) { red[wave][0] = s0; red[wave][1] = q0; red[wave][2] = s1; red[wave][3] = q1; }
  __syncthreads();
  s0 = red[0][0] + red[1][0] + red[2][0] + red[3][0];
  q0 = red[0][1] + red[1][1] + red[2][1] + red[3][1];
  s1 = red[0][2] + red[1][2] + red[2][2] + red[3][2];
  q1 = red[0][3] + red[1][3] + red[2][3] + red[3][3];
  const float mean0 = s0 * (1.f / C_DIM);
  const float inv0 = rsqrtf(q0 * (1.f / C_DIM) - mean0 * mean0 + 1e-5f);
  const float mean1 = s1 * (1.f / C_DIM);
  const float inv1 = rsqrtf(q1 * (1.f / C_DIM) - mean1 * mean1 + 1e-5f);
  float w8[8], b8[8];
  *(float4*)&w8[0] = *(const float4*)(lw + c0);
  *(float4*)&w8[4] = *(const float4*)(lw + c0 + 4);
  *(float4*)&b8[0] = *(const float4*)(lb + c0);
  *(float4*)&b8[4] = *(const float4*)(lb + c0 + 4);
  float ok[8], orr[8];
#pragma unroll
  for (int i = 0; i < 8; ++i) {
    const float cn = (cur[i] - mean0) * inv0 * w8[i] + b8[i];
    const float pn = hp ? ((prv[i] - mean1) * inv1 * w8[i] + b8[i]) : prv[i];
    float a = mk[c0 + i];
    ok[i] = cn * a + pn * (1.f - a);
    a = mr[c0 + i];
    orr[i] = cn * a + pn * (1.f - a);
  }
  *(short8*)(xk2 + rc) = pack_bf8(*(float4*)&ok[0], *(float4*)&ok[4]);
  *(short8*)(xr2 + rc) = pack_bf8(*(float4*)&orr[0], *(float4*)&orr[4]);
}

// ======================= Chunk-parallel WKV v5 scan (bf16 in, f32 state) =======================
__global__ __launch_bounds__(256) void wkv_chunk_sum(const unsigned short* __restrict__ kin,
                                                     const unsigned short* __restrict__ vin,
                                                     const float* __restrict__ decay,
                                                     float* __restrict__ Abuf) {
  const int c = blockIdx.x, h = blockIdx.y;
  const int tid = threadIdx.x;
  const int vcol = tid >> 2, kg = tid & 3;
  __shared__ float ks[CHUNK][HS_DIM];
  __shared__ float vs[CHUNK][HS_DIM];
  for (int i = tid; i < CHUNK * HS_DIM / 8; i += 256) {
    int row = i >> 3, q = i & 7;
    size_t g = (size_t)(c * CHUNK + row) * C_DIM + h * HS_DIM + q * 8;
    short8 kv = *(const short8*)(kin + g);
    short8 vv = *(const short8*)(vin + g);
#pragma unroll
    for (int j = 0; j < 8; ++j) {
      ks[row][q * 8 + j] = bf2f(kv[j]);
      vs[row][q * 8 + j] = bf2f(vv[j]);
    }
  }
  float w16[16], s[16];
#pragma unroll
  for (int j = 0; j < 16; ++j) {
    w16[j] = expf(-expf(decay[h * HS_DIM + kg * 16 + j]));
    s[j] = 0.f;
  }
  __syncthreads();
  for (int t = 0; t < CHUNK; ++t) {
    const float vt = vs[t][vcol];
    const float4* kp = (const float4*)&ks[t][kg * 16];
#pragma unroll
    for (int q = 0; q < 4; ++q) {
      float4 k4 = kp[q];
      s[q * 4 + 0] = __builtin_fmaf(s[q * 4 + 0], w16[q * 4 + 0], k4.x * vt);
      s[q * 4 + 1] = __builtin_fmaf(s[q * 4 + 1], w16[q * 4 + 1], k4.y * vt);
      s[q * 4 + 2] = __builtin_fmaf(s[q * 4 + 2], w16[q * 4 + 2], k4.z * vt);
      s[q * 4 + 3] = __builtin_fmaf(s[q * 4 + 3], w16[q * 4 + 3], k4.w * vt);
    }
  }
  const size_t base = (((size_t)h * NCHUNK + c) * HS_DIM + kg * 16) * HS_DIM + vcol;
#pragma unroll
  for (int j = 0; j < 16; ++j) Abuf[base + (size_t)j * HS_DIM] = s[j];
}

__global__ __launch_bounds__(256) void wkv_chain(const float* __restrict__ Abuf,
                                                 const float* __restrict__ s0,
                                                 const float* __restrict__ decay,
                                                 float* __restrict__ Sbuf) {
  const int h = blockIdx.x;
  const int tid = threadIdx.x;
  const int vcol = tid >> 2, kg = tid & 3;
  float wL[16], s[16];
#pragma unroll
  for (int j = 0; j < 16; ++j) {
    int kidx = kg * 16 + j;
    wL[j] = expf(-(float)CHUNK * expf(decay[h * HS_DIM + kidx]));
    s[j] = s0[((size_t)h * HS_DIM + kidx) * HS_DIM + vcol];
  }
  for (int c = 0; c < NCHUNK; ++c) {
    const size_t base = (((size_t)h * NCHUNK + c) * HS_DIM + kg * 16) * HS_DIM + vcol;
#pragma unroll
    for (int j = 0; j < 16; ++j) {
      Sbuf[base + (size_t)j * HS_DIM] = s[j];
      s[j] = __builtin_fmaf(s[j], wL[j], Abuf[base + (size_t)j * HS_DIM]);
    }
  }
}

// Pass C fused with GroupNorm(out/8)*gn_w+gn_b times silu(g) -> zg bf16
__global__ __launch_bounds__(256) void wkv_chunk_out_gn(
    const unsigned short* __restrict__ kin, const unsigned short* __restrict__ vin,
    const unsigned short* __restrict__ rin, const float* __restrict__ decay,
    const float* __restrict__ faaaa, const float* __restrict__ Sbuf,
    const unsigned short* __restrict__ gpre, const float* __restrict__ gw,
    const float* __restrict__ gb, unsigned short* __restrict__ zg) {
  const int c = blockIdx.x, h = blockIdx.y;
  const int tid = threadIdx.x;
  const int vcol = tid >> 2, kg = tid & 3;
  __shared__ float ks[CHUNK][HS_DIM];
  __shared__ float rs[CHUNK][HS_DIM];
  __shared__ float vs[CHUNK][HS_DIM];
  __shared__ float os[CHUNK][HS_DIM + 4];
  for (int i = tid; i < CHUNK * HS_DIM / 8; i += 256) {
    int row = i >> 3, q = i & 7;
    size_t g = (size_t)(c * CHUNK + row) * C_DIM + h * HS_DIM + q * 8;
    short8 kv = *(const short8*)(kin + g);
    short8 rv = *(const short8*)(rin + g);
    short8 vv = *(const short8*)(vin + g);
#pragma unroll
    for (int j = 0; j < 8; ++j) {
      ks[row][q * 8 + j] = bf2f(kv[j]);
      rs[row][q * 8 + j] = bf2f(rv[j]);
      vs[row][q * 8 + j] = bf2f(vv[j]);
    }
  }
  float w16[16], u16[16], s[16];
  const size_t sbase = (((size_t)h * NCHUNK + c) * HS_DIM + kg * 16) * HS_DIM + vcol;
#pragma unroll
  for (int j = 0; j < 16; ++j) {
    int kidx = kg * 16 + j;
    w16[j] = expf(-expf(decay[h * HS_DIM + kidx]));
    u16[j] = faaaa[h * HS_DIM + kidx];
    s[j] = Sbuf[sbase + (size_t)j * HS_DIM];
  }
  __syncthreads();
  for (int t = 0; t < CHUNK; ++t) {
    const float vt = vs[t][vcol];
    const float4* kp = (const float4*)&ks[t][kg * 16];
    const float4* rp = (const float4*)&rs[t][kg * 16];
    float acc = 0.f, ruk = 0.f;
#pragma unroll
    for (int q = 0; q < 4; ++q) {
      float4 k4 = kp[q], r4 = rp[q];
      acc = __builtin_fmaf(r4.x, s[q * 4 + 0], acc);
      ruk = __builtin_fmaf(r4.x * u16[q * 4 + 0], k4.x, ruk);
      s[q * 4 + 0] = __builtin_fmaf(s[q * 4 + 0], w16[q * 4 + 0], k4.x * vt);
      acc = __builtin_fmaf(r4.y, s[q * 4 + 1], acc);
      ruk = __builtin_fmaf(r4.y * u16[q * 4 + 1], k4.y, ruk);
      s[q * 4 + 1] = __builtin_fmaf(s[q * 4 + 1], w16[q * 4 + 1], k4.y * vt);
      acc = __builtin_fmaf(r4.z, s[q * 4 + 2], acc);
      ruk = __builtin_fmaf(r4.z * u16[q * 4 + 2], k4.z, ruk);
      s[q * 4 + 2] = __builtin_fmaf(s[q * 4 + 2], w16[q * 4 + 2], k4.z * vt);
      acc = __builtin_fmaf(r4.w, s[q * 4 + 3], acc);
      ruk = __builtin_fmaf(r4.w * u16[q * 4 + 3], k4.w, ruk);
      s[q * 4 + 3] = __builtin_fmaf(s[q * 4 + 3], w16[q * 4 + 3], k4.w * vt);
    }
    float part = __builtin_fmaf(ruk, vt, acc);
    part += __shfl_xor(part, 1);
    part += __shfl_xor(part, 2);
    if (kg == 0) os[t][vcol] = part;
  }
  __syncthreads();
  const int tt = tid >> 2, q = tid & 3;
  float z16[16];
  float sm = 0.f, sq2 = 0.f;
#pragma unroll
  for (int j = 0; j < 16; ++j) {
    float z = os[tt][q * 16 + j] * 0.125f;
    z16[j] = z;
    sm += z;
    sq2 = __builtin_fmaf(z, z, sq2);
  }
  sm += __shfl_xor(sm, 1); sq2 += __shfl_xor(sq2, 1);
  sm += __shfl_xor(sm, 2); sq2 += __shfl_xor(sq2, 2);
  const float mean = sm * (1.f / HS_DIM);
  const float inv = rsqrtf(sq2 * (1.f / HS_DIM) - mean * mean + 1e-5f);
  const int ccol = h * HS_DIM + q * 16;
  const size_t obase = (size_t)(c * CHUNK + tt) * C_DIM + ccol;
  float gwv[16], gbv[16];
  *(float4*)&gwv[0] = *(const float4*)(gw + ccol);
  *(float4*)&gwv[4] = *(const float4*)(gw + ccol + 4);
  *(float4*)&gwv[8] = *(const float4*)(gw + ccol + 8);
  *(float4*)&gwv[12] = *(const float4*)(gw + ccol + 12);
  *(float4*)&gbv[0] = *(const float4*)(gb + ccol);
  *(float4*)&gbv[4] = *(const float4*)(gb + ccol + 4);
  *(float4*)&gbv[8] = *(const float4*)(gb + ccol + 8);
  *(float4*)&gbv[12] = *(const float4*)(gb + ccol + 12);
  short8 gp0 = *(const short8*)(gpre + obase);
  short8 gp1 = *(const short8*)(gpre + obase + 8);
  short8 o0, o1;
#pragma unroll
  for (int j = 0; j < 8; ++j) {
    const float g = bf2f(gp0[j]);
    const float sig = 1.f / (1.f + __expf(-g));
    const float val = (z16[j] - mean) * inv * gwv[j] + gbv[j];
    o0[j] = (short)f2bf(val * (g * sig));
  }
#pragma unroll
  for (int j = 0; j < 8; ++j) {
    const float g = bf2f(gp1[j]);
    const float sig = 1.f / (1.f + __expf(-g));
    const float val = (z16[8 + j] - mean) * inv * gwv[8 + j] + gbv[8 + j];
    o1[j] = (short)f2bf(val * (g * sig));
  }
  *(short8*)(zg + obase) = o0;
  *(short8*)(zg + obase + 8) = o1;
}

// ===== bf16-A x f32-B GEMM, BM=128 BN=128 BK=32, wave tile 64x64, pair-barrier =====
struct GemmBatch {
  const unsigned short* A[4];
  const float* B[4];
  void* C[4];
};

template <int EPI, int SPLITK>
__global__ __launch_bounds__(256) void gemm128(GemmBatch gb, int M, int N, int K,
                                               float* __restrict__ P) {
  const int nx = gridDim.x, ny = gridDim.y;
  const int nwg = nx * ny * gridDim.z;
  const int h = (blockIdx.z * ny + blockIdx.y) * nx + blockIdx.x;
  const int chunkw = nwg >> 3;
  const int wrk = (h & 7) * chunkw + (h >> 3);
  const int zz = wrk / (nx * ny);
  const int rem = wrk - zz * (nx * ny);
  const int by = rem % ny;
  const int bx = rem / ny;

  const int s = zz % SPLITK, zb = zz / SPLITK;
  const int Ks = K / SPLITK;
  const int k0 = s * Ks;
  const unsigned short* __restrict__ A = gb.A[zb];
  const float* __restrict__ B = gb.B[zb];
  const int m0 = by * 128, n0 = bx * 128;

  __shared__ unsigned short As[4][128 * 32];
  __shared__ unsigned short Bs[4][128 * 32];

  const int tid = threadIdx.x;
  const int l = tid & 63;
  const int w = tid >> 6;
  const int wm = w >> 1, wn = w & 1;
  const int lrow = l & 15;
  const size_t Kb = (size_t)K * 2;

  const int srow = w * 16 + (l >> 2);
  const int kslot = ((l & 3) ^ ((l >> 3) & 3)) * 16;
  const char* Agl = (const char*)A + (size_t)(m0 + srow) * Kb + kslot;
  const int brl = w * 32 + (l >> 2);
  const int bcol = (l & 3) * 8;

  f32x4 acc[4][4];
#pragma unroll
  for (int m = 0; m < 4; ++m)
#pragma unroll
    for (int n = 0; n < 4; ++n) acc[m][n] = (f32x4){0.f, 0.f, 0.f, 0.f};

#define STGA(buf, kk)                                                        \
  {                                                                          \
    const size_t kb2 = (size_t)(kk) * 2;                                     \
    gl_lds16(Agl + kb2, (char*)&As[buf][0] + w * 1024);                      \
    gl_lds16(Agl + 64 * Kb + kb2, (char*)&As[buf][0] + 4096 + w * 1024);     \
  }

#define LDB(kk, lo0, hi0, lo1, hi1)                                          \
  {                                                                          \
    const float* p0 = B + (size_t)(n0 + brl) * K + (kk) + bcol;              \
    const float* p1 = B + (size_t)(n0 + brl + 16) * K + (kk) + bcol;         \
    lo0 = *(const f32x4*)p0; hi0 = *(const f32x4*)(p0 + 4);                  \
    lo1 = *(const f32x4*)p1; hi1 = *(const f32x4*)(p1 + 4);                  \
  }

#define WRB(buf, lo0, hi0, lo1, hi1)                                         \
  {                                                                          \
    u32x4 q0, q1;                                                            \
    q0[0] = cvtpk(lo0[0], lo0[1]); q0[1] = cvtpk(lo0[2], lo0[3]);            \
    q0[2] = cvtpk(hi0[0], hi0[1]); q0[3] = cvtpk(hi0[2], hi0[3]);            \
    q1[0] = cvtpk(lo1[0], lo1[1]); q1[1] = cvtpk(lo1[2], lo1[3]);            \
    q1[2] = cvtpk(hi1[0], hi1[1]); q1[3] = cvtpk(hi1[2], hi1[3]);            \
    const int sl0 = (l & 3) ^ ((brl >> 1) & 3);                              \
    *(u32x4*)((char*)&Bs[buf][0] + brl * 64 + sl0 * 16) = q0;                \
    *(u32x4*)((char*)&Bs[buf][0] + (brl + 16) * 64 + sl0 * 16) = q1;         \
  }

#define COMPUTE(tt)                                                          \
  {                                                                          \
    const char* Ab = (const char*)&As[(tt) & 3][0];                          \
    const char* Bb = (const char*)&Bs[(tt) & 3][0];                          \
    const int kb = (l >> 4) * 16;                                            \
    const int kbs = kb ^ (((lrow >> 1) & 3) << 4);                           \
    short8 af[4], bfr[4];                                                    \
    _Pragma("unroll") for (int m = 0; m < 4; ++m) {                          \
      const int row = wm * 64 + m * 16 + lrow;                               \
      af[m] = *(const short8*)(Ab + row * 64 + kbs);                         \
    }                                                                        \
    _Pragma("unroll") for (int n = 0; n < 4; ++n) {                          \
      const int row = wn * 64 + n * 16 + lrow;                               \
      bfr[n] = *(const short8*)(Bb + row * 64 + kbs);                        \
    }                                                                        \
    _Pragma("unroll") for (int m = 0; m < 4; ++m)                            \
        _Pragma("unroll") for (int n = 0; n < 4; ++n) acc[m][n] =            \
            __builtin_amdgcn_mfma_f32_16x16x32_bf16(af[m], bfr[n],           \
                                                    acc[m][n], 0, 0, 0);     \
  }

  const int nt = Ks / 32;
  f32x4 bA0, bA1, bA2, bA3, bB0, bB1, bB2, bB3;
  LDB(k0, bA0, bA1, bA2, bA3);
  LDB(k0 + 32, bB0, bB1, bB2, bB3);
  STGA(0, k0);
  STGA(1, k0 + 32);
  WRB(0, bA0, bA1, bA2, bA3);
  WRB(1, bB0, bB1, bB2, bB3);

  for (int t = 0; t < nt; t += 2) {
    asm volatile("s_waitcnt vmcnt(0) lgkmcnt(0)" ::: "memory");
    __builtin_amdgcn_sched_barrier(0);
    __builtin_amdgcn_s_barrier();
    __builtin_amdgcn_sched_barrier(0);
    const bool more = (t + 2 < nt);
    if (more) {
      LDB(k0 + (t + 2) * 32, bA0, bA1, bA2, bA3);
      LDB(k0 + (t + 3) * 32, bB0, bB1, bB2, bB3);
      STGA((t + 2) & 3, k0 + (t + 2) * 32);
      STGA((t + 3) & 3, k0 + (t + 3) * 32);
    }
    COMPUTE(t);
    if (more) {
      WRB((t + 2) & 3, bA0, bA1, bA2, bA3);
      WRB((t + 3) & 3, bB0, bB1, bB2, bB3);
    }
    COMPUTE(t + 1);
  }
#undef STGA
#undef LDB
#undef WRB
#undef COMPUTE

  float* Co;
  if (SPLITK > 1)
    Co = (s == 0) ? (float*)gb.C[zb] : P + (size_t)(s - 1) * M * N;
  else
    Co = (float*)gb.C[zb];

#pragma unroll
  for (int m = 0; m < 4; ++m) {
#pragma unroll
    for (int n = 0; n < 4; ++n) {
#pragma unroll
      for (int j = 0; j < 4; ++j) {
        const int row = m0 + wm * 64 + m * 16 + ((l >> 4) << 2) + j;
        const int col = n0 + wn * 64 + n * 16 + lrow;
        const size_t idx = (size_t)row * N + col;
        const float v = acc[m][n][j];
        if (EPI == 2 && SPLITK == 1) {
          float tpos = v > 0.f ? v : 0.f;
          ((unsigned short*)gb.C[zb])[idx] = f2bf(tpos * tpos);
        } else if (EPI == 3 && SPLITK == 1) {
          ((unsigned short*)gb.C[zb])[idx] = f2bf(v);
        } else {
          Co[idx] = v;
        }
      }
    }
  }
}

// ------ final reduce: out = xnewF + sig(s1+Q0+Q1+Q2) * (C + P0 + P1 + P2) ------
__global__ __launch_bounds__(256) void reduce_final(float* __restrict__ C,
                                                    const float* __restrict__ P,
                                                    const float* __restrict__ E0,
                                                    const float* __restrict__ E1,
                                                    const float* __restrict__ Q,
                                                    size_t n4) {
  for (size_t i = (size_t)blockIdx.x * 256 + threadIdx.x; i < n4;
       i += (size_t)gridDim.x * 256) {
    float4 c = ((const float4*)C)[i];
    float4 p = ((const float4*)P)[i];
    float4 p1 = ((const float4*)P)[i + n4];
    float4 p2 = ((const float4*)P)[i + 2 * n4];
    float4 e0 = ((const float4*)E0)[i];
    float4 e1 = ((const float4*)E1)[i];
    float4 q0 = ((const float4*)Q)[i];
    float4 q1 = ((const float4*)Q)[i + n4];
    float4 q2 = ((const float4*)Q)[i + 2 * n4];
    const float sx = e0.x + q0.x + q1.x + q2.x;
    const float sy = e0.y + q0.y + q1.y + q2.y;
    const float sz = e0.z + q0.z + q1.z + q2.z;
    const float sw = e0.w + q0.w + q1.w + q2.w;
    c.x = e1.x + (1.f / (1.f + __expf(-sx))) * (c.x + p.x + p1.x + p2.x);
    c.y = e1.y + (1.f / (1.f + __expf(-sy))) * (c.y + p.y + p1.y + p2.y);
    c.z = e1.z + (1.f / (1.f + __expf(-sz))) * (c.z + p.z + p1.z + p2.z);
    c.w = e1.w + (1.f / (1.f + __expf(-sw))) * (c.w + p.w + p1.w + p2.w);
    ((float4*)C)[i] = c;
  }
}

extern "C" void kernel_launch(void* const* d_in, const int* in_sizes, int n_in,
                              void* d_out, int out_size, void* d_ws, size_t ws_size,
                              hipStream_t stream) {
  (void)in_sizes; (void)n_in; (void)out_size; (void)ws_size;
  const float* x         = (const float*)d_in[0];
  const float* att_shift = (const float*)d_in[1];
  const float* wkv_state = (const float*)d_in[2];
  const float* ffn_shift = (const float*)d_in[3];
  const float* ln1_w = (const float*)d_in[4];
  const float* ln1_b = (const float*)d_in[5];
  const float* ln2_w = (const float*)d_in[6];
  const float* ln2_b = (const float*)d_in[7];
  const float* tm_k = (const float*)d_in[8];
  const float* tm_v = (const float*)d_in[9];
  const float* tm_r = (const float*)d_in[10];
  const float* tm_g = (const float*)d_in[11];
  const float* time_decay = (const float*)d_in[12];
  const float* time_faaaa = (const float*)d_in[13];
  const float* Wr = (const float*)d_in[14];
  const float* Wk = (const float*)d_in[15];
  const float* Wv = (const float*)d_in[16];
  const float* Wo = (const float*)d_in[17];
  const float* Wg = (const float*)d_in[18];
  const float* gn_w = (const float*)d_in[19];
  const float* gn_b = (const float*)d_in[20];
  const float* cm_k = (const float*)d_in[21];
  const float* cm_r = (const float*)d_in[22];
  const float* Wck = (const float*)d_in[23];
  const float* Wcr = (const float*)d_in[24];
  const float* Wcv = (const float*)d_in[25];
  float* out = (float*)d_out;

  char* act = (char*)d_ws;

  const size_t R = (size_t)T_LEN * C_DIM;        // elements
  const size_t RF = R * 4;                       // f32 bytes
  const size_t RB = R * 2;                       // bf16 bytes
  float*          x1   = (float*)(act);                        // Pgv
  unsigned short* xr_b = (unsigned short*)(act + RF);          // Abuf; Pgv tail
  unsigned short* xk_b = (unsigned short*)(act + RF + RB);
  unsigned short* xv_b = (unsigned short*)(act + RF + 2 * RB); // Sbuf
  unsigned short* xg_b = (unsigned short*)(act + RF + 3 * RB);
  float*          rb   = (float*)(act + RF + 4 * RB);
  float*          kb   = (float*)(act + 2 * RF + 4 * RB);      // k (bf16) + xk2,xr2
  float*          vb   = (float*)(act + 3 * RF + 4 * RB);      // v (bf16); kk_b spans vb+gpre
  float*          gpre = (float*)(act + 4 * RF + 4 * RB);      // gpre (bf16)
  unsigned short* zg_b = (unsigned short*)(act + 5 * RF + 4 * RB);
  float*          xnew = (float*)(act + 5 * RF + 5 * RB);      // go split0 partial
  float*          s1   = (float*)(act + 6 * RF + 5 * RB);
  float*          xnewF = (float*)(act + 7 * RF + 5 * RB);     // final xnew
  float*          Pgo_m = (float*)(act + 8 * RF + 5 * RB);     // go splits 1-3 (3*RF)
  float*          Pgr_m = (float*)(act + 11 * RF + 5 * RB);    // gr splits 1-3 (3*RF)
  // aliases
  float*          Abuf  = (float*)xr_b;
  float*          Sbuf  = (float*)xv_b;
  unsigned short* rb_b  = (unsigned short*)rb;
  unsigned short* kb_b  = (unsigned short*)kb;
  unsigned short* vb_b  = (unsigned short*)vb;
  unsigned short* gp_b  = (unsigned short*)gpre;
  unsigned short* xk2_b = (unsigned short*)kb;                 // kb dead after wkv
  unsigned short* xr2_b = (unsigned short*)((char*)kb + RB);
  unsigned short* kk_b  = (unsigned short*)vb;                 // spans vb+gpre
  float*          Pgv   = x1;            // 25.2 MB (x1 + xr..xg), dead during Wcv GEMM

  dim3 blk(256);
  const size_t n4 = R / 4;

  // --- TimeMix ---
  ln_mix_att<<<T_LEN, blk, 0, stream>>>(x, att_shift, ln1_w, ln1_b,
                                        tm_r, tm_k, tm_v, tm_g,
                                        xr_b, xk_b, xv_b, xg_b);
  GemmBatch g4 = {};
  g4.A[0] = xr_b; g4.B[0] = Wr; g4.C[0] = rb_b;
  g4.A[1] = xk_b; g4.B[1] = Wk; g4.C[1] = kb_b;
  g4.A[2] = xv_b; g4.B[2] = Wv; g4.C[2] = vb_b;
  g4.A[3] = xg_b; g4.B[3] = Wg; g4.C[3] = gp_b;
  gemm128<3, 1><<<dim3(16, 8, 4), blk, 0, stream>>>(g4, T_LEN, C_DIM, C_DIM, nullptr);

  // chunk-parallel WKV scan (bf16 inputs, f32 state) + fused GroupNorm/silu
  wkv_chunk_sum<<<dim3(NCHUNK, H_NUM), blk, 0, stream>>>(kb_b, vb_b, time_decay, Abuf);
  wkv_chain<<<H_NUM, blk, 0, stream>>>(Abuf, wkv_state, time_decay, Sbuf);
  wkv_chunk_out_gn<<<dim3(NCHUNK, H_NUM), blk, 0, stream>>>(
      kb_b, vb_b, rb_b, time_decay, time_faaaa, Sbuf, gp_b, gn_w, gn_b, zg_b);

  GemmBatch go = {};
  go.A[0] = zg_b; go.B[0] = Wo; go.C[0] = xnew;
  gemm128<0, 4><<<dim3(16, 8, 4), blk, 0, stream>>>(go, T_LEN, C_DIM, C_DIM, Pgo_m);

  // --- ChannelMix (xnew composed inline from 4 partials; writes final xnew + mixes) ---
  ln_mix_cm_f<<<T_LEN, blk, 0, stream>>>(xnew, Pgo_m, x, ffn_shift, ln2_w, ln2_b,
                                         cm_k, cm_r, xnewF, xk2_b, xr2_b);

  GemmBatch gk = {};
  gk.A[0] = xk2_b; gk.B[0] = Wck; gk.C[0] = kk_b;
  gemm128<2, 1><<<dim3(56, 8, 1), blk, 0, stream>>>(gk, T_LEN, FF_DIM, C_DIM, nullptr);

  GemmBatch gr = {};
  gr.A[0] = xr2_b; gr.B[0] = Wcr; gr.C[0] = s1;
  gemm128<0, 4><<<dim3(16, 8, 4), blk, 0, stream>>>(gr, T_LEN, C_DIM, C_DIM, Pgr_m);

  GemmBatch gv = {};
  gv.A[0] = kk_b; gv.B[0] = Wcv; gv.C[0] = out;
  gemm128<0, 4><<<dim3(16, 8, 4), blk, 0, stream>>>(gv, T_LEN, C_DIM, FF_DIM, Pgv);
  reduce_final<<<2048, blk, 0, stream>>>(out, Pgv, s1, xnewF, Pgr_m, n4);
}